// Round 2
// baseline (268.821 us; speedup 1.0000x reference)
//
#include <hip/hip_runtime.h>

// Problem constants (fixed by reference):
//   N=16384 spatial, R=16 feat, P=4096 blocks, T=64 out-feat, B=8 batch
#define C_N 16384
#define C_R 16
#define C_P 4096
#define C_B 8

// One workgroup (256 thr = 4 waves) per block p. Wave w owns the K-quarter
// i in [w*16, w*16+16); lane = output column o. Each wave reads only its
// quarter of the 4 weight matrices (total HBM weight traffic unchanged,
// 4x more workgroups for latency hiding: grid 4096 -> up to 8 WG/CU with
// 20 KB LDS and <=64 VGPR). Partials reduced through LDS at the end.
__global__ __launch_bounds__(256, 8)
void butterfly_local_conv(const float* __restrict__ x,
                          const float* __restrict__ Wrr,
                          const float* __restrict__ Wri,
                          const float* __restrict__ Wir,
                          const float* __restrict__ Wii,
                          const int*   __restrict__ perm,
                          float* __restrict__ out)
{
    __shared__ float xs[2][C_B][64];          // [c][b][i]  4 KB
    __shared__ float partial[4][2][C_B][64];  // [wave][c][b][o]  16 KB

    const int t = threadIdx.x;
    const int p = blockIdx.x;

    // ---- stage permuted x into LDS: one float4 per thread, conflict-free
    {
        const int c = t >> 7;        // 0..1
        const int b = (t >> 4) & 7;  // 0..7
        const int s = (t >> 2) & 3;  // 0..3 (kernel window position)
        const int q = t & 3;         // float4 index within row of 16
        const int n = perm[4 * p + s];
        const float4 v = ((const float4*)(x + (((size_t)(b * 2 + c)) * C_N + n) * C_R))[q];
        ((float4*)&xs[c][b][0])[s * 4 + q] = v;
    }
    __syncthreads();

    const int w = t >> 6;       // K-quarter (and wave id)
    const int o = t & 63;       // output column
    const int ibase = w * 16;

    float acc_re[C_B], acc_im[C_B];
    #pragma unroll
    for (int b = 0; b < C_B; ++b) { acc_re[b] = 0.0f; acc_im[b] = 0.0f; }

    const size_t wbase = (size_t)p * 64 * 64 + (size_t)ibase * 64 + o;
    const float* __restrict__ wrr_p = Wrr + wbase;
    const float* __restrict__ wri_p = Wri + wbase;
    const float* __restrict__ wir_p = Wir + wbase;
    const float* __restrict__ wii_p = Wii + wbase;

    // K-loop over this wave's 16 i's, chunked by 4 (x comes as ds_read_b128,
    // weight loads get constant 256 B immediate offsets after unroll).
    #pragma unroll
    for (int k0 = 0; k0 < 16; k0 += 4) {
        float wrr[4], wri[4], wir[4], wii[4];
        #pragma unroll
        for (int k = 0; k < 4; ++k) {
            const int off = (k0 + k) * 64;
            wrr[k] = wrr_p[off];
            wri[k] = wri_p[off];
            wir[k] = wir_p[off];
            wii[k] = wii_p[off];
        }
        #pragma unroll
        for (int b = 0; b < C_B; ++b) {
            const float4 xr4 = *(const float4*)(&xs[0][b][ibase + k0]);
            const float4 xi4 = *(const float4*)(&xs[1][b][ibase + k0]);
            acc_re[b] = fmaf(xr4.x, wrr[0], acc_re[b]);
            acc_re[b] = fmaf(xi4.x, wri[0], acc_re[b]);
            acc_im[b] = fmaf(xr4.x, wir[0], acc_im[b]);
            acc_im[b] = fmaf(xi4.x, wii[0], acc_im[b]);

            acc_re[b] = fmaf(xr4.y, wrr[1], acc_re[b]);
            acc_re[b] = fmaf(xi4.y, wri[1], acc_re[b]);
            acc_im[b] = fmaf(xr4.y, wir[1], acc_im[b]);
            acc_im[b] = fmaf(xi4.y, wii[1], acc_im[b]);

            acc_re[b] = fmaf(xr4.z, wrr[2], acc_re[b]);
            acc_re[b] = fmaf(xi4.z, wri[2], acc_re[b]);
            acc_im[b] = fmaf(xr4.z, wir[2], acc_im[b]);
            acc_im[b] = fmaf(xi4.z, wii[2], acc_im[b]);

            acc_re[b] = fmaf(xr4.w, wrr[3], acc_re[b]);
            acc_re[b] = fmaf(xi4.w, wri[3], acc_re[b]);
            acc_im[b] = fmaf(xr4.w, wir[3], acc_im[b]);
            acc_im[b] = fmaf(xi4.w, wii[3], acc_im[b]);
        }
    }

    // ---- write partials (lane-stride-1 dwords: conflict-free)
    #pragma unroll
    for (int b = 0; b < C_B; ++b) {
        partial[w][0][b][o] = acc_re[b];
        partial[w][1][b][o] = acc_im[b];
    }
    __syncthreads();

    // ---- reduce 4 K-quarters and store. Thread t handles o = t&63 and
    // 4 (c,b) combos; lanes within a wave share (c,b) -> 256 B coalesced stores.
    #pragma unroll
    for (int j = 0; j < 4; ++j) {
        const int cb = (t >> 6) * 4 + j;   // 0..15
        const int c = cb >> 3;
        const int b = cb & 7;
        const float s = partial[0][c][b][o] + partial[1][c][b][o]
                      + partial[2][c][b][o] + partial[3][c][b][o];
        out[((size_t)(b * 2 + c)) * (C_N * C_R) + (size_t)p * 64 + o] = s;
    }
}

extern "C" void kernel_launch(void* const* d_in, const int* in_sizes, int n_in,
                              void* d_out, int out_size, void* d_ws, size_t ws_size,
                              hipStream_t stream) {
    const float* x    = (const float*)d_in[0];
    const float* Wrr  = (const float*)d_in[1];
    const float* Wri  = (const float*)d_in[2];
    const float* Wir  = (const float*)d_in[3];
    const float* Wii  = (const float*)d_in[4];
    const int*   perm = (const int*)d_in[5];
    float* out = (float*)d_out;

    // One WG per block p: grid 4096 x 256 threads.
    butterfly_local_conv<<<dim3(C_P), dim3(256), 0, stream>>>(
        x, Wrr, Wri, Wir, Wii, perm, out);
}